// Round 2
// baseline (148.902 us; speedup 1.0000x reference)
//
#include <hip/hip_runtime.h>
#include <hip/hip_bf16.h>

typedef unsigned short u16;
typedef unsigned int u32;

// guide §3 (learn_hip-verified): gfx950 mfma bf16 builtins take short8 fragments.
typedef __attribute__((ext_vector_type(8))) short bf16x8;
typedef __attribute__((ext_vector_type(4))) float floatx4;

__device__ __forceinline__ float bf2f(u16 u) {
    union { u32 i; float f; } v; v.i = ((u32)u) << 16; return v.f;
}
__device__ __forceinline__ u16 f2bf(float f) {
    union { float f; u32 i; } v; v.f = f;
    u32 r = v.i + 0x7FFFu + ((v.i >> 16) & 1u);  // RNE
    return (u16)(r >> 16);
}

#define DD 512
#define NTOK 128

// ---------------------------------------------------------------------------
// Kernel C: features fp32 -> bf16 (1024x512 = 524288 elems), vectorized.
// ---------------------------------------------------------------------------
__global__ __launch_bounds__(256) void convert_features(
    const float* __restrict__ src, u16* __restrict__ dst)
{
    const int i = (blockIdx.x * 256 + threadIdx.x) * 8;  // grid covers exactly
    float4 a = *(const float4*)(src + i);
    float4 b = *(const float4*)(src + i + 4);
    u16 v[8] = { f2bf(a.x), f2bf(a.y), f2bf(a.z), f2bf(a.w),
                 f2bf(b.x), f2bf(b.y), f2bf(b.z), f2bf(b.w) };
    *(uint4*)(dst + i) = *(uint4*)v;
}

// ---------------------------------------------------------------------------
// Kernel T: fp32 -> bf16 transposes. z=0: W1[0:512,:]->W1aT(512x512);
// z=1: W1[512:1024,:]->W1bT; z=2: W2(512x256)->W2T(256x512).
// ---------------------------------------------------------------------------
__global__ __launch_bounds__(256) void transpose_k(
    const float* __restrict__ W1, const float* __restrict__ W2,
    u16* __restrict__ W1aT, u16* __restrict__ W1bT, u16* __restrict__ W2T)
{
    const int z = blockIdx.z;
    const float* src; u16* dst; int rows, cols;
    if (z == 0)      { src = W1;             dst = W1aT; rows = 512; cols = 512; }
    else if (z == 1) { src = W1 + 512 * 512; dst = W1bT; rows = 512; cols = 512; }
    else             { src = W2;             dst = W2T;  rows = 512; cols = 256; }
    const int c0 = blockIdx.x * 32, r0 = blockIdx.y * 32;
    if (c0 >= cols || r0 >= rows) return;
    __shared__ u16 tile[32][33];
    const int tx = threadIdx.x & 31, ty = threadIdx.x >> 5;  // 32 x 8
#pragma unroll
    for (int i = 0; i < 4; ++i) {
        int r = ty + i * 8;
        tile[r][tx] = f2bf(src[(size_t)(r0 + r) * cols + (c0 + tx)]);
    }
    __syncthreads();
#pragma unroll
    for (int i = 0; i < 4; ++i) {
        int r = ty + i * 8;
        dst[(size_t)(c0 + r) * rows + (r0 + tx)] = tile[tx][r];
    }
}

// ---------------------------------------------------------------------------
// Kernel 1: layer-1 GEMM. Hf = Fbf(1024x512,bf16) @ W1x (via W1xT, N-major).
// Grid (8 Mtiles, 4 Ntiles, 2 which). 256 thr = 4 waves (2x2), wave tile 64x64.
// ---------------------------------------------------------------------------
__global__ __launch_bounds__(256) void gemm_layer1(
    const u16* __restrict__ Fbf, const u16* __restrict__ W1T,  // W1aT then W1bT contiguous
    u16* __restrict__ Hf1, u16* __restrict__ Hf2)
{
    const u16* Bt = W1T + (size_t)blockIdx.z * 512 * 512;
    u16* outp = blockIdx.z ? Hf2 : Hf1;
    const int bM = blockIdx.x, bN = blockIdx.y;
    __shared__ __align__(16) u16 Atile[128 * 64];
    __shared__ __align__(16) u16 Btile[128 * 64];
    const int tid = threadIdx.x;
    const int wid = tid >> 6, lane = tid & 63;
    const int wm = wid >> 1, wn = wid & 1;
    const int lrow = lane & 15, quad = lane >> 4;

    floatx4 acc[4][4];
#pragma unroll
    for (int i = 0; i < 4; ++i)
#pragma unroll
        for (int j = 0; j < 4; ++j) acc[i][j] = (floatx4)(0.0f);

    for (int kc = 0; kc < 8; ++kc) {
        const int k0 = kc * 64;
        {   // stage A: t -> (m = tid>>1, seg = tid&1), 32 bf16 = 4 uint4, XOR-swizzled
            const int m = tid >> 1, seg = tid & 1, sw = m & 7;
            const uint4* src = (const uint4*)(Fbf + (size_t)(bM * 128 + m) * DD + k0 + seg * 32);
#pragma unroll
            for (int j = 0; j < 4; ++j)
                *(uint4*)(Atile + m * 64 + (((seg * 4 + j) ^ sw) << 3)) = src[j];
        }
        {   // stage B
            const int c = tid >> 1, seg = tid & 1, sw = c & 7;
            const uint4* src = (const uint4*)(Bt + (size_t)(bN * 128 + c) * DD + k0 + seg * 32);
#pragma unroll
            for (int j = 0; j < 4; ++j)
                *(uint4*)(Btile + c * 64 + (((seg * 4 + j) ^ sw) << 3)) = src[j];
        }
        __syncthreads();
#pragma unroll
        for (int ks = 0; ks < 2; ++ks) {
            bf16x8 af[4], bfr[4];
            const int ch = ks * 4 + quad;
#pragma unroll
            for (int i = 0; i < 4; ++i) {
                int r = wm * 64 + i * 16 + lrow;
                af[i] = *(const bf16x8*)(Atile + r * 64 + ((ch ^ (r & 7)) << 3));
            }
#pragma unroll
            for (int j = 0; j < 4; ++j) {
                int c = wn * 64 + j * 16 + lrow;
                bfr[j] = *(const bf16x8*)(Btile + c * 64 + ((ch ^ (c & 7)) << 3));
            }
#pragma unroll
            for (int i = 0; i < 4; ++i)
#pragma unroll
                for (int j = 0; j < 4; ++j)
                    acc[i][j] = __builtin_amdgcn_mfma_f32_16x16x32_bf16(af[i], bfr[j], acc[i][j], 0, 0, 0);
        }
        __syncthreads();
    }
#pragma unroll
    for (int i = 0; i < 4; ++i)
#pragma unroll
        for (int j = 0; j < 4; ++j)
#pragma unroll
            for (int r = 0; r < 4; ++r) {
                int row = bM * 128 + wm * 64 + i * 16 + quad * 4 + r;
                int col = bN * 128 + wn * 64 + j * 16 + lrow;
                outp[(size_t)row * DD + col] = f2bf(acc[i][j][r]);
            }
}

// ---------------------------------------------------------------------------
// Main fused kernel: one block per (n, b). 512 thr = 8 waves (2x4), wave 64x64.
// H built on-the-fly into swizzled LDS; MFMA vs W2T; epilogue relu + layer-3.
// Output fp32.
// ---------------------------------------------------------------------------
__global__ __launch_bounds__(512) void fused_main(
    const u16* __restrict__ Hf1, const u16* __restrict__ Hf2,
    const u16* __restrict__ W2T, const float* __restrict__ W1,
    const float* __restrict__ b1, const float* __restrict__ b2,
    const float* __restrict__ W3, const float* __restrict__ b3,
    const float* __restrict__ positions, float* __restrict__ out)
{
    const int n = blockIdx.x, b = blockIdx.y;
    const int tid = threadIdx.x;
    const int base_bn = b * NTOK + n;

    __shared__ float s1[DD];            // Hf1[b,n,:] + b1
    __shared__ float w1c0[DD], w1c1[DD];
    __shared__ float pdx[NTOK], pdy[NTOK];
    __shared__ float W3T[4][260];       // W3 transposed, fp32
    // Union region: (Atile 16KB + Btile 32KB) main loop  |  g half-tile 34816B epilogue
    __shared__ __align__(16) char mainbuf[49152];
    u16* Atile = (u16*)mainbuf;            // [128][64] swizzled
    u16* Btile = (u16*)(mainbuf + 16384);  // [256][64] swizzled
    u16* gh    = (u16*)mainbuf;            // [128][136] epilogue

    // ---- phase 0: broadcasts ----
    {
        int k = tid; // 512 threads, DD = 512
        s1[k]   = bf2f(Hf1[(size_t)base_bn * DD + k]) + b1[k];
        w1c0[k] = W1[(size_t)1024 * DD + k];
        w1c1[k] = W1[(size_t)1025 * DD + k];
    }
    if (tid < NTOK) {
        float pnx = positions[(size_t)base_bn * 2 + 0];
        float pny = positions[(size_t)base_bn * 2 + 1];
        int mb = b * NTOK + tid;
        pdx[tid] = pnx - positions[(size_t)mb * 2 + 0];
        pdy[tid] = pny - positions[(size_t)mb * 2 + 1];
    }
    if (tid < 256) {
#pragma unroll
        for (int o = 0; o < 4; ++o) W3T[o][tid] = W3[tid * 4 + o];
    }
    __syncthreads();

    const int wid = tid >> 6, lane = tid & 63;
    const int wm = wid >> 2, wn = wid & 3;          // 2 x 4 wave grid
    const int lrow = lane & 15, quad = lane >> 4;

    floatx4 acc[4][4];
#pragma unroll
    for (int i = 0; i < 4; ++i)
#pragma unroll
        for (int j = 0; j < 4; ++j) acc[i][j] = (floatx4)(0.0f);

    // ---- main loop over K chunks of 64 ----
    for (int kc = 0; kc < 8; ++kc) {
        const int k0 = kc * 64;
        {   // stage A (H tile): t -> (m = tid>>2, seg = tid&3), 16 elems
            const int m = tid >> 2, seg = tid & 3;
            const uint4* src = (const uint4*)(Hf2 + (size_t)(b * NTOK + m) * DD + k0 + seg * 16);
            uint4 d0 = src[0], d1 = src[1];
            __align__(16) u16 inv[16];
            *(uint4*)&inv[0] = d0; *(uint4*)&inv[8] = d1;
            const float px = pdx[m], py = pdy[m];
            __align__(16) u16 vals[16];
#pragma unroll
            for (int j = 0; j < 16; ++j) {
                int k = k0 + seg * 16 + j;
                float h = bf2f(inv[j]) + s1[k] + px * w1c0[k] + py * w1c1[k];
                vals[j] = f2bf(fmaxf(h, 0.0f));
            }
            const int sw = m & 7, c0 = seg * 2;
            *(uint4*)(Atile + m * 64 + (((c0    ) ^ sw) << 3)) = *(uint4*)&vals[0];
            *(uint4*)(Atile + m * 64 + (((c0 + 1) ^ sw) << 3)) = *(uint4*)&vals[8];
        }
        {   // stage B (W2T tile): t -> (c = tid>>1, seg = tid&1), 32 elems
            const int c = tid >> 1, seg = tid & 1, sw = c & 7;
            const uint4* src = (const uint4*)(W2T + (size_t)c * DD + k0 + seg * 32);
#pragma unroll
            for (int j = 0; j < 4; ++j)
                *(uint4*)(Btile + c * 64 + (((seg * 4 + j) ^ sw) << 3)) = src[j];
        }
        __syncthreads();
#pragma unroll
        for (int ks = 0; ks < 2; ++ks) {
            bf16x8 af[4], bfr[4];
            const int ch = ks * 4 + quad;
#pragma unroll
            for (int i = 0; i < 4; ++i) {
                int r = wm * 64 + i * 16 + lrow;
                af[i] = *(const bf16x8*)(Atile + r * 64 + ((ch ^ (r & 7)) << 3));
            }
#pragma unroll
            for (int j = 0; j < 4; ++j) {
                int c = wn * 64 + j * 16 + lrow;
                bfr[j] = *(const bf16x8*)(Btile + c * 64 + ((ch ^ (c & 7)) << 3));
            }
#pragma unroll
            for (int i = 0; i < 4; ++i)
#pragma unroll
                for (int j = 0; j < 4; ++j)
                    acc[i][j] = __builtin_amdgcn_mfma_f32_16x16x32_bf16(af[i], bfr[j], acc[i][j], 0, 0, 0);
        }
        __syncthreads();
    }

    // ---- epilogue: bias+relu -> g (bf16, two column-halves), then layer-3 dot ----
    float b2v[4];
#pragma unroll
    for (int j = 0; j < 4; ++j) b2v[j] = b2[wn * 64 + j * 16 + lrow];

    const int row3 = tid >> 2, o3 = tid & 3;
    float a3 = b3[o3];

    for (int half = 0; half < 2; ++half) {
        __syncthreads();   // protect gh region (overlaps A/B tiles; prior reads done)
        if ((wn >> 1) == half) {
#pragma unroll
            for (int i = 0; i < 4; ++i)
#pragma unroll
                for (int j = 0; j < 4; ++j)
#pragma unroll
                    for (int r = 0; r < 4; ++r) {
                        int row = wm * 64 + i * 16 + quad * 4 + r;
                        int col = (wn & 1) * 64 + j * 16 + lrow;  // local col in half
                        float v = acc[i][j][r] + b2v[j];
                        gh[row * 136 + col] = f2bf(fmaxf(v, 0.0f));
                    }
        }
        __syncthreads();
#pragma unroll
        for (int l = 0; l < 128; l += 8) {
            uint4 gv = *(const uint4*)(gh + row3 * 136 + l);
            const u16* gu = (const u16*)&gv;
#pragma unroll
            for (int j = 0; j < 8; ++j)
                a3 += bf2f(gu[j]) * W3T[o3][half * 128 + l + j];
        }
    }
    // out[b][n][m=row3][o3], fully coalesced fp32: flat index = base_bn*512 + tid
    out[(size_t)base_bn * 512 + tid] = a3;
}

// ---------------------------------------------------------------------------
extern "C" void kernel_launch(void* const* d_in, const int* in_sizes, int n_in,
                              void* d_out, int out_size, void* d_ws, size_t ws_size,
                              hipStream_t stream)
{
    const float* features  = (const float*)d_in[0];
    const float* positions = (const float*)d_in[1];
    const float* W1 = (const float*)d_in[2];
    const float* b1 = (const float*)d_in[3];
    const float* W2 = (const float*)d_in[4];
    const float* b2 = (const float*)d_in[5];
    const float* W3 = (const float*)d_in[6];
    const float* b3 = (const float*)d_in[7];
    float* out = (float*)d_out;

    char* ws = (char*)d_ws;
    u16* W1aT = (u16*)(ws);                 // 512*512*2 = 524288 B
    u16* W1bT = (u16*)(ws + 524288);        // 524288 B
    u16* W2T  = (u16*)(ws + 1048576);       // 256*512*2 = 262144 B
    u16* Fbf  = (u16*)(ws + 1310720);       // 1024*512*2 = 1048576 B
    u16* Hf1  = (u16*)(ws + 2359296);       // 1048576 B
    u16* Hf2  = (u16*)(ws + 3407872);       // 1048576 B  (total 4.25 MB)

    convert_features<<<dim3(256), 256, 0, stream>>>(features, Fbf);
    transpose_k<<<dim3(16, 16, 3), 256, 0, stream>>>(W1, W2, W1aT, W1bT, W2T);
    gemm_layer1<<<dim3(8, 4, 2), 256, 0, stream>>>(Fbf, W1aT, Hf1, Hf2);
    fused_main<<<dim3(128, 8), 512, 0, stream>>>(Hf1, Hf2, W2T, W1, b1, b2, W3, b3,
                                                 positions, out);
}